// Round 7
// baseline (239.102 us; speedup 1.0000x reference)
//
#include <hip/hip_runtime.h>

#define BATCH 200000
#define ITERS 100
#define NPTS 101
#define BLK 256                   // 4 waves; wave 0 scans, all 4 sweep
#define ELEMS 64                  // elements per block (= scan lanes)
#define ROWF 202                  // floats per element row (101 pts * 2), 808 B
#define SPANF (ELEMS * ROWF)      // 12928 floats = 51712 B per block
#define SPAN4 (SPANF / 4)         // 3232 float4s (51712 = 64*808: line-aligned)

// 64 elements/block staged full-row in LDS (51712 B -> 3 blocks/CU), but with
// 4 waves/block -> 12 waves/CU (3/SIMD): co-resident scan waves hide each
// other's fma dep-chain + h-load latency, sweep issues 4x wider, and one
// block's store drain overlaps another's scan. Output sweep is one perfectly
// contiguous 64B-aligned dwordx4 stream (no partial-line RMW).
__global__ void ifs_traj_kernel(const float* __restrict__ coef,
                                const float* __restrict__ h,
                                float* __restrict__ out) {
    __shared__ float lds[SPANF];

    const int tid = threadIdx.x;
    const int b0  = blockIdx.x * ELEMS;     // BATCH = 3125*64 exactly

    if (tid < ELEMS) {
        const int b = b0 + tid;

        const float4* c4 = (const float4*)(coef + (size_t)b * 12);
        const float4 ca0 = c4[0];   // c0 c1 c2 c3
        const float4 ca1 = c4[1];   // c4 c5 c6 c7
        const float4 ca2 = c4[2];   // c8 c9 c10 c11

        const float j0 = fabsf(ca0.x * ca0.w - ca0.y * ca0.z);
        const float j1 = fabsf(ca1.z * ca2.y - ca1.w * ca2.x);
        const float p  = j0 / (j0 + j1);

        // All 100 h loads issued up-front: ~25.6 KB in flight per scan wave.
        float hv[ITERS];
        #pragma unroll
        for (int t = 0; t < ITERS; ++t) {
            hv[t] = h[(size_t)t * BATCH + b];
        }

        float2* row2 = (float2*)(lds + tid * ROWF);   // 808B pitch, 8B-aligned
        float x = 0.05f, y = 0.05f;
        row2[0] = make_float2(x, y);

        #pragma unroll
        for (int t = 0; t < ITERS; ++t) {
            const float ht = hv[t];
            const bool useB = ht > p;
            const float m0 = useB ? ca1.z : ca0.x;
            const float m1 = useB ? ca1.w : ca0.y;
            const float m2 = useB ? ca2.x : ca0.z;
            const float m3 = useB ? ca2.y : ca0.w;
            const float m4 = useB ? ca2.z : ca1.x;
            const float m5 = useB ? ca2.w : ca1.y;
            const float xn = fmaf(m0, x, fmaf(m1, y, m4));
            const float yn = fmaf(m2, x, fmaf(m3, y, m5));
            x = xn; y = yn;
            row2[t + 1] = make_float2(x, y);          // ds_write_b64, 4 words/bank
        }
    }

    __syncthreads();   // publish LDS scan results to all 4 waves

    // Contiguous sweep: block span [b0*808B, +51712B) == lds[0..51712B).
    // 256 threads x 13 rounds of float4 (ds_read_b128 8/bank = minimum).
    const float4* lsrc = (const float4*)lds;
    float4* dst = (float4*)(out + (size_t)b0 * ROWF);
    #pragma unroll
    for (int r = 0; r < 13; ++r) {
        const int idx = r * BLK + tid;
        if (idx < SPAN4) {                 // 12*256=3072 full; round 13 partial
            dst[idx] = lsrc[idx];
        }
    }
}

extern "C" void kernel_launch(void* const* d_in, const int* in_sizes, int n_in,
                              void* d_out, int out_size, void* d_ws, size_t ws_size,
                              hipStream_t stream) {
    const float* coef = (const float*)d_in[0];   // (BATCH, 12) f32
    const float* h    = (const float*)d_in[1];   // (ITERS, BATCH) f32
    float* out        = (float*)d_out;           // (BATCH, 101, 2) f32

    const int grid = BATCH / ELEMS;              // 3125 exact
    ifs_traj_kernel<<<grid, BLK, 0, stream>>>(coef, h, out);
}